// Round 1
// baseline (394.178 us; speedup 1.0000x reference)
//
#include <hip/hip_runtime.h>
#include <math.h>

#define B_  64
#define T_  4096
#define QD_ 1024
#define AD_ 256
#define MASKVAL (-1e30f)

// ---------------------------------------------------------------------------
// Kernel A: pq[b][d] = dot(query[b,:], Wq[d,:])   (B x AD output, tiny)
// grid = B, block = AD (=256)
// ---------------------------------------------------------------------------
__global__ __launch_bounds__(256) void pq_kernel(const float* __restrict__ query,
                                                 const float* __restrict__ Wq,
                                                 float* __restrict__ pq) {
    __shared__ float qs[QD_];
    const int b   = blockIdx.x;
    const int tid = threadIdx.x;          // 0..255
    // Stage query row into LDS: 1024 floats, 256 threads, one float4 each.
    ((float4*)qs)[tid] = ((const float4*)(query + (size_t)b * QD_))[tid];
    __syncthreads();

    const int d = tid;
    const float4* w4 = (const float4*)(Wq + (size_t)d * QD_);
    float sum = 0.f;
#pragma unroll 8
    for (int k = 0; k < QD_ / 4; ++k) {
        const float4 w = w4[k];
        const float4 q = ((const float4*)qs)[k];   // same addr all lanes -> broadcast
        sum += q.x * w.x + q.y * w.y + q.z * w.z + q.w * w.w;
    }
    pq[(size_t)b * AD_ + d] = sum;
}

// ---------------------------------------------------------------------------
// Kernel B: energies[b,t] = sum_d tanh(pq[b,d] + pm[b,t,d]) * v[d],
//           or MASKVAL where mask is set (wave-uniform skip -> no pm load).
// One wave per (b,t). block = 256 (4 waves), grid = B*T/4.
// ---------------------------------------------------------------------------
__global__ __launch_bounds__(256) void energy_kernel(const float* __restrict__ pm,
                                                     const int*   __restrict__ mask,
                                                     const float* __restrict__ pq,
                                                     const float* __restrict__ v,
                                                     float* __restrict__ energies) {
    const int wave = threadIdx.x >> 6;                      // 0..3
    const int lane = threadIdx.x & 63;                      // 0..63
    const size_t idx = (size_t)blockIdx.x * 4 + wave;       // flattened b*T + t
    const int b = (int)(idx >> 12);                         // T = 4096 = 2^12

    if (mask[idx]) {                                        // wave-uniform branch
        if (lane == 0) energies[idx] = MASKVAL;
        return;
    }

    // 64 lanes x float4 = 256 floats = whole AD row, perfectly coalesced 1 KiB.
    const float4 m  = ((const float4*)pm)[idx * (AD_ / 4) + lane];
    const float4 q  = ((const float4*)(pq + (size_t)b * AD_))[lane];
    const float4 vv = ((const float4*)v)[lane];

    float e = tanhf(q.x + m.x) * vv.x
            + tanhf(q.y + m.y) * vv.y
            + tanhf(q.z + m.z) * vv.z
            + tanhf(q.w + m.w) * vv.w;

    // wave64 butterfly reduction
#pragma unroll
    for (int off = 32; off > 0; off >>= 1)
        e += __shfl_xor(e, off, 64);

    if (lane == 0) energies[idx] = e;
}

// ---------------------------------------------------------------------------
// Kernel C: row softmax over T per batch. grid = B, block = 256.
// Each thread owns 4 float4 (16 elems): 256*16 = 4096 = T.
// ---------------------------------------------------------------------------
__global__ __launch_bounds__(256) void softmax_kernel(const float* __restrict__ energies,
                                                      float* __restrict__ out) {
    const int b    = blockIdx.x;
    const int tid  = threadIdx.x;
    const int wave = tid >> 6;
    const int lane = tid & 63;
    __shared__ float redmax[4];
    __shared__ float redsum[4];

    const float4* e4 = (const float4*)(energies + (size_t)b * T_);
    float4 vals[4];
    float mx = -INFINITY;
#pragma unroll
    for (int i = 0; i < 4; ++i) {
        vals[i] = e4[i * 256 + tid];
        mx = fmaxf(mx, fmaxf(fmaxf(vals[i].x, vals[i].y), fmaxf(vals[i].z, vals[i].w)));
    }
#pragma unroll
    for (int off = 32; off > 0; off >>= 1)
        mx = fmaxf(mx, __shfl_xor(mx, off, 64));
    if (lane == 0) redmax[wave] = mx;
    __syncthreads();
    mx = fmaxf(fmaxf(redmax[0], redmax[1]), fmaxf(redmax[2], redmax[3]));

    float s = 0.f;
#pragma unroll
    for (int i = 0; i < 4; ++i) {
        vals[i].x = expf(vals[i].x - mx);
        vals[i].y = expf(vals[i].y - mx);
        vals[i].z = expf(vals[i].z - mx);
        vals[i].w = expf(vals[i].w - mx);
        s += vals[i].x + vals[i].y + vals[i].z + vals[i].w;
    }
#pragma unroll
    for (int off = 32; off > 0; off >>= 1)
        s += __shfl_xor(s, off, 64);
    if (lane == 0) redsum[wave] = s;
    __syncthreads();
    s = redsum[0] + redsum[1] + redsum[2] + redsum[3];

    const float inv = 1.f / s;
    float4* o4 = (float4*)(out + (size_t)b * T_);
#pragma unroll
    for (int i = 0; i < 4; ++i) {
        vals[i].x *= inv; vals[i].y *= inv; vals[i].z *= inv; vals[i].w *= inv;
        o4[i * 256 + tid] = vals[i];
    }
}

// ---------------------------------------------------------------------------
extern "C" void kernel_launch(void* const* d_in, const int* in_sizes, int n_in,
                              void* d_out, int out_size, void* d_ws, size_t ws_size,
                              hipStream_t stream) {
    const float* query = (const float*)d_in[0];   // (B, QD)
    const float* pm    = (const float*)d_in[1];   // (B, T, AD)
    const int*   mask  = (const int*)  d_in[2];   // (B, T) bool -> int32
    const float* Wq    = (const float*)d_in[3];   // (AD, QD)
    const float* v     = (const float*)d_in[4];   // (AD,)
    float* out = (float*)d_out;                   // (B, T)

    float* pq       = (float*)d_ws;                       // B*AD floats (64 KiB)
    float* energies = pq + (size_t)B_ * AD_;              // B*T floats (1 MiB)

    pq_kernel<<<B_, 256, 0, stream>>>(query, Wq, pq);
    energy_kernel<<<(B_ * T_) / 4, 256, 0, stream>>>(pm, mask, pq, v, energies);
    softmax_kernel<<<B_, 256, 0, stream>>>(energies, out);
}

// Round 2
// 341.820 us; speedup vs baseline: 1.1532x; 1.1532x over previous
//
#include <hip/hip_runtime.h>
#include <math.h>

#define B_  64
#define T_  4096
#define QD_ 1024
#define AD_ 256
#define MASKVAL (-1e30f)
#define LOG2E 1.44269504f

// tanh(x) = (e-1)/(e+1), e = 2^(2x*log2e). Clamp |x|<=9: tanh(9)=1-3e-8,
// keeps exp2 in range. v_exp_f32 / v_rcp_f32 are ~1 ulp -> abs err ~1e-6,
// vs 9e-5 harness threshold (round-1 absmax was 3.8e-6, 24x headroom).
__device__ __forceinline__ float tanh_fast(float x) {
    float xc = fminf(fmaxf(x, -9.0f), 9.0f);
    float e  = __builtin_amdgcn_exp2f(xc * (2.0f * LOG2E));
    return (e - 1.0f) * __builtin_amdgcn_rcpf(e + 1.0f);
}

// ---------------------------------------------------------------------------
// Kernel A: pq[b][d] = dot(query[b,:], Wq[d,:]).
// One wave per (b,d): lanes stride K -> coalesced Wq/query row reads.
// grid = B*AD/4 = 4096 blocks, 256 threads (4 waves).
// ---------------------------------------------------------------------------
__global__ __launch_bounds__(256) void pq_kernel(const float* __restrict__ query,
                                                 const float* __restrict__ Wq,
                                                 float* __restrict__ pq) {
    const int wave = threadIdx.x >> 6;
    const int lane = threadIdx.x & 63;
    const int w = blockIdx.x * 4 + wave;     // 0 .. B*AD-1
    const int b = w >> 8;                    // w / AD_
    const int d = w & 255;                   // w % AD_

    const float4* q4 = (const float4*)(query + (size_t)b * QD_);
    const float4* w4 = (const float4*)(Wq + (size_t)d * QD_);
    float sum = 0.f;
#pragma unroll
    for (int j = 0; j < QD_ / 4 / 64; ++j) {    // 4 iters
        const float4 a = q4[j * 64 + lane];
        const float4 c = w4[j * 64 + lane];
        sum += a.x * c.x + a.y * c.y + a.z * c.z + a.w * c.w;
    }
#pragma unroll
    for (int off = 32; off > 0; off >>= 1)
        sum += __shfl_xor(sum, off, 64);
    if (lane == 0) pq[w] = sum;              // w == b*AD + d
}

// ---------------------------------------------------------------------------
// Kernel B: energies[b,t] = sum_d tanh(pq[b,d] + pm[b,t,d]) * v[d]  (or MASKVAL).
// One wave handles 4 consecutive t: 4 independent 1 KiB loads in flight,
// mask as int4, pq/v amortized. Scalar (readfirstlane) mask branches.
// grid = B*T/16 = 16384 blocks, 256 threads.
// ---------------------------------------------------------------------------
__global__ __launch_bounds__(256) void energy_kernel(const float* __restrict__ pm,
                                                     const int*   __restrict__ mask,
                                                     const float* __restrict__ pq,
                                                     const float* __restrict__ v,
                                                     float* __restrict__ energies) {
    const int wave = threadIdx.x >> 6;
    const int lane = threadIdx.x & 63;
    const size_t grp = (size_t)blockIdx.x * 4 + wave;  // group of 4 consecutive (b,t)
    const size_t t0  = grp * 4;                        // flattened b*T + t
    const int b = (int)(t0 >> 12);                     // T = 4096

    const int4 mk = ((const int4*)mask)[grp];
    const int msk0 = __builtin_amdgcn_readfirstlane(mk.x);
    const int msk1 = __builtin_amdgcn_readfirstlane(mk.y);
    const int msk2 = __builtin_amdgcn_readfirstlane(mk.z);
    const int msk3 = __builtin_amdgcn_readfirstlane(mk.w);
    const int msk[4] = {msk0, msk1, msk2, msk3};

    const float4 q  = ((const float4*)(pq + (size_t)b * AD_))[lane];
    const float4 vv = ((const float4*)v)[lane];

    const float4* pm4 = (const float4*)pm;
    float4 m[4];
#pragma unroll
    for (int i = 0; i < 4; ++i)                         // issue loads back-to-back
        if (!msk[i]) m[i] = pm4[(t0 + i) * (AD_ / 4) + lane];

    float res[4];
#pragma unroll
    for (int i = 0; i < 4; ++i) {
        if (msk[i]) { res[i] = MASKVAL; continue; }
        float e = tanh_fast(q.x + m[i].x) * vv.x
                + tanh_fast(q.y + m[i].y) * vv.y
                + tanh_fast(q.z + m[i].z) * vv.z
                + tanh_fast(q.w + m[i].w) * vv.w;
#pragma unroll
        for (int off = 32; off > 0; off >>= 1)
            e += __shfl_xor(e, off, 64);
        res[i] = e;
    }
    if (lane == 0)
        ((float4*)energies)[grp] = make_float4(res[0], res[1], res[2], res[3]);
}

// ---------------------------------------------------------------------------
// Kernel C: row softmax over T per batch. grid = B, block = 512 (8 waves).
// Each thread owns 2 float4 (8 elems): 512*8 = 4096 = T.
// ---------------------------------------------------------------------------
__global__ __launch_bounds__(512) void softmax_kernel(const float* __restrict__ energies,
                                                      float* __restrict__ out) {
    const int b    = blockIdx.x;
    const int tid  = threadIdx.x;
    const int wave = tid >> 6;
    const int lane = tid & 63;
    __shared__ float redmax[8];
    __shared__ float redsum[8];

    const float4* e4 = (const float4*)(energies + (size_t)b * T_);
    float4 v0 = e4[tid];
    float4 v1 = e4[tid + 512];

    float mx = fmaxf(fmaxf(fmaxf(v0.x, v0.y), fmaxf(v0.z, v0.w)),
                     fmaxf(fmaxf(v1.x, v1.y), fmaxf(v1.z, v1.w)));
#pragma unroll
    for (int off = 32; off > 0; off >>= 1)
        mx = fmaxf(mx, __shfl_xor(mx, off, 64));
    if (lane == 0) redmax[wave] = mx;
    __syncthreads();
#pragma unroll
    for (int i = 0; i < 8; ++i) mx = fmaxf(mx, redmax[i]);

    v0.x = __builtin_amdgcn_exp2f((v0.x - mx) * LOG2E);
    v0.y = __builtin_amdgcn_exp2f((v0.y - mx) * LOG2E);
    v0.z = __builtin_amdgcn_exp2f((v0.z - mx) * LOG2E);
    v0.w = __builtin_amdgcn_exp2f((v0.w - mx) * LOG2E);
    v1.x = __builtin_amdgcn_exp2f((v1.x - mx) * LOG2E);
    v1.y = __builtin_amdgcn_exp2f((v1.y - mx) * LOG2E);
    v1.z = __builtin_amdgcn_exp2f((v1.z - mx) * LOG2E);
    v1.w = __builtin_amdgcn_exp2f((v1.w - mx) * LOG2E);
    float s = v0.x + v0.y + v0.z + v0.w + v1.x + v1.y + v1.z + v1.w;
#pragma unroll
    for (int off = 32; off > 0; off >>= 1)
        s += __shfl_xor(s, off, 64);
    if (lane == 0) redsum[wave] = s;
    __syncthreads();
    s = 0.f;
#pragma unroll
    for (int i = 0; i < 8; ++i) s += redsum[i];

    const float inv = 1.f / s;
    float4* o4 = (float4*)(out + (size_t)b * T_);
    v0.x *= inv; v0.y *= inv; v0.z *= inv; v0.w *= inv;
    v1.x *= inv; v1.y *= inv; v1.z *= inv; v1.w *= inv;
    o4[tid]       = v0;
    o4[tid + 512] = v1;
}

// ---------------------------------------------------------------------------
extern "C" void kernel_launch(void* const* d_in, const int* in_sizes, int n_in,
                              void* d_out, int out_size, void* d_ws, size_t ws_size,
                              hipStream_t stream) {
    const float* query = (const float*)d_in[0];   // (B, QD)
    const float* pm    = (const float*)d_in[1];   // (B, T, AD)
    const int*   mask  = (const int*)  d_in[2];   // (B, T) bool -> int32
    const float* Wq    = (const float*)d_in[3];   // (AD, QD)
    const float* v     = (const float*)d_in[4];   // (AD,)
    float* out = (float*)d_out;                   // (B, T)

    float* pq       = (float*)d_ws;                       // B*AD floats (64 KiB)
    float* energies = pq + (size_t)B_ * AD_;              // B*T floats (1 MiB)

    pq_kernel<<<(B_ * AD_) / 4, 256, 0, stream>>>(query, Wq, pq);
    energy_kernel<<<(B_ * T_) / 16, 256, 0, stream>>>(pm, mask, pq, v, energies);
    softmax_kernel<<<B_, 512, 0, stream>>>(energies, out);
}